// Round 17
// baseline (233.175 us; speedup 1.0000x reference)
//
#include <hip/hip_runtime.h>
#include <hip/hip_bf16.h>
#include <math.h>

// ---------------------------------------------------------------------------
// GATConv forward.  N=100000, E=1.6M, IN=128, OUT*HEADS=128 (OUT=32, H=4).
// Round 17 (= r15 base + dispatch-tail cuts):
//   - gemm_deg: interleaved {gemm tiles} + {XCD-privatized deg_rank} (r15).
//   - nscan: per-node 8-copy prefix + deg + block scan, WITH FUSED final
//     block-sum scan (last-block pattern, threadfence + done counter) --
//     scan2 dispatch eliminated.
//   - fill: unchanged (r15).
//   - gather: r15 pipelined two-phase + NONTEMPORAL sorted_col loads
//     (6.4MB streamed once; keep L2 for Zh).
//   Zh row layout: dword d (= o'*4+h) holds channels (o'*4+h, (o'+16)*4+h);
//   ushort slot s(ch) = (o&15)*8 + h*2 + (o>>4).
// ---------------------------------------------------------------------------

typedef __attribute__((ext_vector_type(8))) short bf16x8;
typedef __attribute__((ext_vector_type(4))) float f32x4;

__device__ __forceinline__ ushort f2bf(float f) {
  __hip_bfloat16 h = __float2bfloat16(f);   // RNE
  return __builtin_bit_cast(ushort, h);
}
__device__ __forceinline__ float bf2f(ushort u) {
  unsigned v = ((unsigned)u) << 16;
  return __builtin_bit_cast(float, v);
}

// ---- fused: interleaved {gemm tiles} + {XCD-privatized deg_rank chunks} ----
__global__ __launch_bounds__(512, 4) void gemm_deg(
    const float* __restrict__ x, const float* __restrict__ W,
    const float* __restrict__ bias,
    const float* __restrict__ a_l, const float* __restrict__ a_r,
    ushort* __restrict__ Zh, float* __restrict__ el, float* __restrict__ er,
    int N, const int* __restrict__ row, int* __restrict__ cntP,
    int* __restrict__ rank, int E, int G1, int ilv) {
  __shared__ __align__(16) ushort smem[16896];   // xh[128*128] ; reused zs[128*132]
  __shared__ float sal[128], sar[128];

  const int b = (int)blockIdx.x;
  int tile = -1, tailt = -1;
  if (ilv) {
    if ((b % 5 == 0) && (b / 5 < G1)) tile = b / 5;
    else {
      int g = (b + 4) / 5;             // gemm blocks with index < b
      if (g > G1) g = G1;
      tailt = b - g;
    }
  } else {
    if (b < G1) tile = b; else tailt = b - G1;
  }

  if (tile < 0) {
    int e = tailt * 512 + (int)threadIdx.x;
    if (e < E) {
      int copy = b & 7;                // tracks round-robin block->XCD
      rank[e] = atomicAdd(&cntP[copy * N + row[e]], 1);
    }
    return;
  }

  const int t = threadIdx.x;
  const int lane = t & 63;
  const int wv = t >> 6;                 // wave id: owns channels wv*16..+15
  const int row0 = tile * 128;
  const int l15 = lane & 15, l4 = lane >> 4;
  const int ch = wv * 16 + l15;          // ref channel = o*4+h

  if (t < 128) { sal[t] = a_l[t]; sar[t] = a_r[t]; }

  // ---- B fragments: W f32 -> bf16 hi/lo in-register (W is L2-resident) ----
  bf16x8 Bh[4], Bl[4];
#pragma unroll
  for (int kf = 0; kf < 4; ++kf) {
    const float* wp = W + (size_t)ch * 128 + kf * 32 + l4 * 8;
    float4 w0 = *(const float4*)(wp);
    float4 w1 = *(const float4*)(wp + 4);
    float wf[8] = {w0.x, w0.y, w0.z, w0.w, w1.x, w1.y, w1.z, w1.w};
    bf16x8 hi, lo;
#pragma unroll
    for (int j = 0; j < 8; ++j) {
      ushort hb = f2bf(wf[j]);
      hi[j] = (short)hb;
      lo[j] = (short)f2bf(wf[j] - bf2f(hb));
    }
    Bh[kf] = hi;
    Bl[kf] = lo;
  }

  // ---- stage x tile (128 rows) -> LDS bf16 hi, 16B-chunk XOR swizzle ----
  ushort* xh = smem;
#pragma unroll
  for (int i = 0; i < 8; ++i) {
    int f4 = i * 512 + t;                // 4096 float4s
    int r = f4 >> 5;
    int k = (f4 & 31) * 4;
    int gr = row0 + r;
    float4 v = make_float4(0.f, 0.f, 0.f, 0.f);
    if (gr < N) v = ((const float4*)x)[(size_t)gr * 32 + (f4 & 31)];
    int idx = r * 128 + (k ^ ((r & 7) << 3));
    uint2 hv;
    hv.x = f2bf(v.x) | ((unsigned)f2bf(v.y) << 16);
    hv.y = f2bf(v.z) | ((unsigned)f2bf(v.w) << 16);
    *(uint2*)&xh[idx] = hv;
  }
  __syncthreads();

  // ---- MFMA: 8 row-tiles x 4 k-frags x 2 products, 1 ch-tile/wave ----
  f32x4 acc[8];
#pragma unroll
  for (int rt = 0; rt < 8; ++rt) acc[rt] = (f32x4){0.f, 0.f, 0.f, 0.f};

#pragma unroll
  for (int kf = 0; kf < 4; ++kf) {
#pragma unroll
    for (int rt = 0; rt < 8; ++rt) {
      int r = rt * 16 + l15;
      int idx = r * 128 + ((kf * 32 + l4 * 8) ^ ((r & 7) << 3));
      bf16x8 ah = *(const bf16x8*)&xh[idx];
      acc[rt] = __builtin_amdgcn_mfma_f32_16x16x32_bf16(ah, Bh[kf], acc[rt], 0, 0, 0);
      acc[rt] = __builtin_amdgcn_mfma_f32_16x16x32_bf16(ah, Bl[kf], acc[rt], 0, 0, 0);
    }
  }
  __syncthreads();   // xh dead; reuse as zs

  // ---- acc -> LDS packed-slot tile ----
  // slot s(ch): o=ch>>2, h=ch&3, o'=o&15 -> s = o'*8 + h*2 + (o>>4)
  ushort* zs = smem;   // [128][132]
  {
    float bv = bias[ch];
    int o = ch >> 2, h = ch & 3;
    int s = (o & 15) * 8 + h * 2 + (o >> 4);
#pragma unroll
    for (int rt = 0; rt < 8; ++rt) {
#pragma unroll
      for (int j = 0; j < 4; ++j) {
        int r = rt * 16 + l4 * 4 + j;
        zs[r * 132 + s] = f2bf(acc[rt][j] + bv);
      }
    }
  }
  __syncthreads();

  // ---- coalesced Zh stores + fused el/er (4 threads/row, 1 head each) ----
  {
    int r = t >> 2;                 // 0..127
    int h = t & 3;                  // head AND store chunk
    int gr = row0 + r;
    if (gr < N) {
#pragma unroll
      for (int q = 0; q < 4; ++q) {
        uint4 v = *(const uint4*)&zs[r * 132 + h * 32 + q * 8];
        *(uint4*)&Zh[(size_t)gr * 128 + h * 32 + q * 8] = v;
      }
      float sl = 0.f, sr = 0.f;
#pragma unroll
      for (int op = 0; op < 16; ++op) {
        unsigned zz = *(const unsigned*)&zs[r * 132 + op * 8 + h * 2];
        float zlo = bf2f((ushort)(zz & 0xffff));     // channel op*4+h
        float zhi = bf2f((ushort)(zz >> 16));        // channel (op+16)*4+h
        int c = (op << 2) + h;
        sl += zlo * sal[c] + zhi * sal[c + 64];
        sr += zlo * sar[c] + zhi * sar[c + 64];
      }
      el[(unsigned)gr * 4 + h] = sl;
      er[(unsigned)gr * 4 + h] = sr;
    }
  }
}

// ---- per-node copy prefix + deg + block scan + FUSED final bsum scan ----
__global__ __launch_bounds__(256) void nscan(
    int* __restrict__ cntP, int* __restrict__ deg, int* __restrict__ base,
    int* __restrict__ bsum, int* __restrict__ done, int N, int NB) {
  __shared__ int ss[256];
  __shared__ int s2[512];
  __shared__ int isLast;
  int t = threadIdx.x;
  int i = blockIdx.x * 256 + t;
  int tot = 0;
  if (i < N) {
    int run = 0;
#pragma unroll
    for (int k = 0; k < 8; ++k) {
      int c = cntP[k * N + i];
      cntP[k * N + i] = run;       // exclusive offset of copy k
      run += c;
    }
    tot = run;
  }
  ss[t] = tot;
  __syncthreads();
#pragma unroll
  for (int off = 1; off < 256; off <<= 1) {
    int u = (t >= off) ? ss[t - off] : 0;
    __syncthreads();
    ss[t] += u;
    __syncthreads();
  }
  if (i < N) {
    base[i] = ss[t] - tot;         // exclusive within block
    deg[i] = tot;
  }
  if (t == 255) bsum[blockIdx.x] = ss[255];

  // ---- last block performs the (exclusive) scan of bsum[0..NB) ----
  __threadfence();
  if (t == 0) {
    int v = atomicAdd(done, 1);
    isLast = (v == NB - 1);
  }
  __syncthreads();
  if (!isLast) return;
  __threadfence();                  // acquire: make other blocks' bsum visible
  s2[t] = (t < NB) ? bsum[t] : 0;
  s2[t + 256] = (t + 256 < NB) ? bsum[t + 256] : 0;
  __syncthreads();
  if (t == 0) {                     // serial exclusive scan in LDS (NB<=512)
    int run = 0;
    for (int k = 0; k < NB; ++k) {
      int c = s2[k];
      s2[k] = run;
      run += c;
    }
  }
  __syncthreads();
  if (t < NB) bsum[t] = s2[t];
  if (t + 256 < NB) bsum[t + 256] = s2[t + 256];
}

__global__ __launch_bounds__(256) void fill(
    const int* __restrict__ row, const int* __restrict__ col,
    const int* __restrict__ rank, const int* __restrict__ base,
    const int* __restrict__ bsum, const int* __restrict__ cntP,
    int* __restrict__ sorted_col, int E, int N, int G1, int ilv) {
  int e = blockIdx.x * 256 + threadIdx.x;
  if (e >= E) return;
  int r = row[e];
  int t9 = e >> 9;                   // 512-edge tail chunk index
  int b = ilv ? ((t9 >> 2) * 5 + (t9 & 3) + 1)   // inverse of interleave map
              : (G1 + t9);
  int copy = b & 7;
  int pos = base[r] + bsum[r >> 8] + cntP[copy * N + r] + rank[e];
  sorted_col[pos] = col[e];
}

__global__ __launch_bounds__(256) void gather(
    const int* __restrict__ base, const int* __restrict__ bsum,
    const int* __restrict__ deg, const int* __restrict__ sorted_col,
    const float* __restrict__ el, const float* __restrict__ er,
    const ushort* __restrict__ Zh, float* __restrict__ out, int N) {
  int t = threadIdx.x;
  int lane = t & 63;
  int n = blockIdx.x * 4 + (t >> 6);
  if (n >= N) return;
  int h = lane & 3;                   // head
  int jj = lane >> 2;                 // edge sub-index within 16-chunk
  int s = base[n] + bsum[n >> 8];
  int d = deg[n];
  int end = s + d;
  float elv = el[((unsigned)n << 2) + h];
  float acc0 = 0.f, acc1 = 0.f, sumA = 0.f;
  const unsigned* Zh32 = (const unsigned*)Zh;
  const unsigned zlane = (unsigned)lane;
  const int bpb = (lane & 3) << 2;    // bpermute byte base: source = jj*4+h

  // phase A for chunk at pp: one exp per (edge,head) -> packed (cl, bf16(xv))
  auto phaseA = [&](int pp) -> unsigned {
    unsigned pkv = 0;
    if (pp + jj < end) {
      int cl = __builtin_nontemporal_load(&sorted_col[pp + jj]);
      float e = elv + er[((unsigned)cl << 2) + h];
      e = fmaxf(e, 0.2f * e);          // LeakyReLU(0.2)
      float x = __expf(e);
      sumA += x;
      pkv = ((unsigned)cl << 15) | (f2bf(x) & 0x7fffu);  // xv>0 -> sign bit 0
    }
    return pkv;
  };

  unsigned pk = (s < end) ? phaseA(s) : 0;
  for (int p = s; p < end; p += 16) {
    // phase B issue: bpermute broadcast + address calc + Zh loads
    float xvb[16];
    unsigned addrv[16];
#pragma unroll
    for (int q = 0; q < 16; ++q) {
      int a = bpb + (q << 4);          // source lane q*4+h
      unsigned bb = (unsigned)__builtin_amdgcn_ds_bpermute(a, (int)pk);
      addrv[q] = ((bb >> 15) << 6) + zlane;
      xvb[q] = bf2f((ushort)(bb & 0x7fffu));
    }
    unsigned zz[16];
#pragma unroll
    for (int q = 0; q < 16; ++q) zz[q] = Zh32[addrv[q]];
    // phase A of NEXT chunk runs here -- hides the 16 outstanding loads.
    int np = p + 16;
    unsigned pk2 = (np < end) ? phaseA(np) : 0;
#pragma unroll
    for (int q = 0; q < 16; ++q) {
      acc0 = fmaf(xvb[q], __builtin_bit_cast(float, zz[q] << 16), acc0);
      acc1 = fmaf(xvb[q], __builtin_bit_cast(float, zz[q] & 0xffff0000u), acc1);
    }
    pk = pk2;
  }
  // reduce denom over the 16 lanes of this head (bits 2..5)
  float sum = sumA;
  sum += __shfl_xor(sum, 4, 64);
  sum += __shfl_xor(sum, 8, 64);
  sum += __shfl_xor(sum, 16, 64);
  sum += __shfl_xor(sum, 32, 64);
  float inv = (d > 0) ? 1.0f / sum : 0.f;
  // lane = o'*4+h exactly -> coalesced stores
  unsigned ob = ((unsigned)n << 7) + zlane;
  __builtin_nontemporal_store(acc0 * inv, &out[ob]);
  __builtin_nontemporal_store(acc1 * inv, &out[ob + 64]);
}

extern "C" void kernel_launch(void* const* d_in, const int* in_sizes, int n_in,
                              void* d_out, int out_size, void* d_ws, size_t ws_size,
                              hipStream_t stream) {
  const float* x   = (const float*)d_in[0];
  const int*   row = (const int*)d_in[1];
  const int*   col = (const int*)d_in[2];
  const float* W   = (const float*)d_in[3];
  const float* b   = (const float*)d_in[4];
  const float* a_l = (const float*)d_in[5];
  const float* a_r = (const float*)d_in[6];
  float* out = (float*)d_out;

  const int N = in_sizes[0] / 128;
  const int E = in_sizes[1];
  const int NB = (N + 255) / 256;

  char* w = (char*)d_ws;
  ushort* Zh       = (ushort*)w;             w += (size_t)N * 128 * 2;
  int*   sorted_col= (int*)w;                w += (size_t)E * 4;
  int*   rank      = (int*)w;                w += (size_t)E * 4;
  float* el        = (float*)w;              w += (size_t)N * 4 * 4;
  float* er        = (float*)w;              w += (size_t)N * 4 * 4;
  int*   cntP      = (int*)w;                w += (size_t)N * 8 * 4;
  int*   deg       = (int*)w;                w += (size_t)N * 4;
  int*   base      = (int*)w;                w += (size_t)N * 4;
  int*   bsum      = (int*)w;                w += 512 * 4;
  int*   done      = (int*)w;                w += 4;

  // zero cntP and the adjacent deg/base/bsum/done region in one memset
  hipMemsetAsync(cntP, 0,
                 ((size_t)N * 8 + (size_t)N * 2 + 512 + 1) * sizeof(int),
                 stream);

  const int G1 = (N + 127) / 128;            // gemm tiles
  const int G2 = (E + 511) / 512;            // 512-edge tail chunks
  const int ilv = ((G1 - 1) * 5 < G1 + G2) ? 1 : 0;
  gemm_deg<<<G1 + G2, 512, 0, stream>>>(x, W, b, a_l, a_r, Zh, el, er,
                                        N, row, cntP, rank, E, G1, ilv);

  nscan<<<NB, 256, 0, stream>>>(cntP, deg, base, bsum, done, N, NB);
  fill<<<(E + 255) / 256, 256, 0, stream>>>(row, col, rank, base, bsum, cntP,
                                            sorted_col, E, N, G1, ilv);
  gather<<<(N + 3) / 4, 256, 0, stream>>>(base, bsum, deg, sorted_col, el, er,
                                          Zh, out, N);
}

// Round 18
// 199.775 us; speedup vs baseline: 1.1672x; 1.1672x over previous
//
#include <hip/hip_runtime.h>
#include <hip/hip_bf16.h>
#include <math.h>

// ---------------------------------------------------------------------------
// GATConv forward.  N=100000, E=1.6M, IN=128, OUT*HEADS=128 (OUT=32, H=4).
// Round 18 = exact revert to round-15 structure (best: 200.6us).
//   r17's two "safe" cuts both regressed (+32us): last-block nscan fusion
//   (391 device-scope threadfences > one 3us scan2 dispatch) and nontemporal
//   sorted_col loads (those lines DO benefit from L2).
//   - gemm_deg: interleaved {gemm tiles} + {XCD-privatized deg_rank}.
//   - nscan / scan2 / fill: separate small dispatches.
//   - gather: pipelined two-phase wave gather, packed bpermute, plain loads.
//   Zh row layout: dword d (= o'*4+h) holds channels (o'*4+h, (o'+16)*4+h);
//   ushort slot s(ch) = (o&15)*8 + h*2 + (o>>4).
// ---------------------------------------------------------------------------

typedef __attribute__((ext_vector_type(8))) short bf16x8;
typedef __attribute__((ext_vector_type(4))) float f32x4;

__device__ __forceinline__ ushort f2bf(float f) {
  __hip_bfloat16 h = __float2bfloat16(f);   // RNE
  return __builtin_bit_cast(ushort, h);
}
__device__ __forceinline__ float bf2f(ushort u) {
  unsigned v = ((unsigned)u) << 16;
  return __builtin_bit_cast(float, v);
}

// ---- fused: interleaved {gemm tiles} + {XCD-privatized deg_rank chunks} ----
__global__ __launch_bounds__(512, 4) void gemm_deg(
    const float* __restrict__ x, const float* __restrict__ W,
    const float* __restrict__ bias,
    const float* __restrict__ a_l, const float* __restrict__ a_r,
    ushort* __restrict__ Zh, float* __restrict__ el, float* __restrict__ er,
    int N, const int* __restrict__ row, int* __restrict__ cntP,
    int* __restrict__ rank, int E, int G1, int ilv) {
  __shared__ __align__(16) ushort smem[16896];   // xh[128*128] ; reused zs[128*132]
  __shared__ float sal[128], sar[128];

  const int b = (int)blockIdx.x;
  int tile = -1, tailt = -1;
  if (ilv) {
    if ((b % 5 == 0) && (b / 5 < G1)) tile = b / 5;
    else {
      int g = (b + 4) / 5;             // gemm blocks with index < b
      if (g > G1) g = G1;
      tailt = b - g;
    }
  } else {
    if (b < G1) tile = b; else tailt = b - G1;
  }

  if (tile < 0) {
    int e = tailt * 512 + (int)threadIdx.x;
    if (e < E) {
      int copy = b & 7;                // tracks round-robin block->XCD
      rank[e] = atomicAdd(&cntP[copy * N + row[e]], 1);
    }
    return;
  }

  const int t = threadIdx.x;
  const int lane = t & 63;
  const int wv = t >> 6;                 // wave id: owns channels wv*16..+15
  const int row0 = tile * 128;
  const int l15 = lane & 15, l4 = lane >> 4;
  const int ch = wv * 16 + l15;          // ref channel = o*4+h

  if (t < 128) { sal[t] = a_l[t]; sar[t] = a_r[t]; }

  // ---- B fragments: W f32 -> bf16 hi/lo in-register (W is L2-resident) ----
  bf16x8 Bh[4], Bl[4];
#pragma unroll
  for (int kf = 0; kf < 4; ++kf) {
    const float* wp = W + (size_t)ch * 128 + kf * 32 + l4 * 8;
    float4 w0 = *(const float4*)(wp);
    float4 w1 = *(const float4*)(wp + 4);
    float wf[8] = {w0.x, w0.y, w0.z, w0.w, w1.x, w1.y, w1.z, w1.w};
    bf16x8 hi, lo;
#pragma unroll
    for (int j = 0; j < 8; ++j) {
      ushort hb = f2bf(wf[j]);
      hi[j] = (short)hb;
      lo[j] = (short)f2bf(wf[j] - bf2f(hb));
    }
    Bh[kf] = hi;
    Bl[kf] = lo;
  }

  // ---- stage x tile (128 rows) -> LDS bf16 hi, 16B-chunk XOR swizzle ----
  ushort* xh = smem;
#pragma unroll
  for (int i = 0; i < 8; ++i) {
    int f4 = i * 512 + t;                // 4096 float4s
    int r = f4 >> 5;
    int k = (f4 & 31) * 4;
    int gr = row0 + r;
    float4 v = make_float4(0.f, 0.f, 0.f, 0.f);
    if (gr < N) v = ((const float4*)x)[(size_t)gr * 32 + (f4 & 31)];
    int idx = r * 128 + (k ^ ((r & 7) << 3));
    uint2 hv;
    hv.x = f2bf(v.x) | ((unsigned)f2bf(v.y) << 16);
    hv.y = f2bf(v.z) | ((unsigned)f2bf(v.w) << 16);
    *(uint2*)&xh[idx] = hv;
  }
  __syncthreads();

  // ---- MFMA: 8 row-tiles x 4 k-frags x 2 products, 1 ch-tile/wave ----
  f32x4 acc[8];
#pragma unroll
  for (int rt = 0; rt < 8; ++rt) acc[rt] = (f32x4){0.f, 0.f, 0.f, 0.f};

#pragma unroll
  for (int kf = 0; kf < 4; ++kf) {
#pragma unroll
    for (int rt = 0; rt < 8; ++rt) {
      int r = rt * 16 + l15;
      int idx = r * 128 + ((kf * 32 + l4 * 8) ^ ((r & 7) << 3));
      bf16x8 ah = *(const bf16x8*)&xh[idx];
      acc[rt] = __builtin_amdgcn_mfma_f32_16x16x32_bf16(ah, Bh[kf], acc[rt], 0, 0, 0);
      acc[rt] = __builtin_amdgcn_mfma_f32_16x16x32_bf16(ah, Bl[kf], acc[rt], 0, 0, 0);
    }
  }
  __syncthreads();   // xh dead; reuse as zs

  // ---- acc -> LDS packed-slot tile ----
  // slot s(ch): o=ch>>2, h=ch&3, o'=o&15 -> s = o'*8 + h*2 + (o>>4)
  ushort* zs = smem;   // [128][132]
  {
    float bv = bias[ch];
    int o = ch >> 2, h = ch & 3;
    int s = (o & 15) * 8 + h * 2 + (o >> 4);
#pragma unroll
    for (int rt = 0; rt < 8; ++rt) {
#pragma unroll
      for (int j = 0; j < 4; ++j) {
        int r = rt * 16 + l4 * 4 + j;
        zs[r * 132 + s] = f2bf(acc[rt][j] + bv);
      }
    }
  }
  __syncthreads();

  // ---- coalesced Zh stores + fused el/er (4 threads/row, 1 head each) ----
  {
    int r = t >> 2;                 // 0..127
    int h = t & 3;                  // head AND store chunk
    int gr = row0 + r;
    if (gr < N) {
#pragma unroll
      for (int q = 0; q < 4; ++q) {
        uint4 v = *(const uint4*)&zs[r * 132 + h * 32 + q * 8];
        *(uint4*)&Zh[(size_t)gr * 128 + h * 32 + q * 8] = v;
      }
      float sl = 0.f, sr = 0.f;
#pragma unroll
      for (int op = 0; op < 16; ++op) {
        unsigned zz = *(const unsigned*)&zs[r * 132 + op * 8 + h * 2];
        float zlo = bf2f((ushort)(zz & 0xffff));     // channel op*4+h
        float zhi = bf2f((ushort)(zz >> 16));        // channel (op+16)*4+h
        int c = (op << 2) + h;
        sl += zlo * sal[c] + zhi * sal[c + 64];
        sr += zlo * sar[c] + zhi * sar[c + 64];
      }
      el[(unsigned)gr * 4 + h] = sl;
      er[(unsigned)gr * 4 + h] = sr;
    }
  }
}

// ---- per-node copy prefix (in place) + deg + block scan ----
__global__ __launch_bounds__(256) void nscan(
    int* __restrict__ cntP, int* __restrict__ deg, int* __restrict__ base,
    int* __restrict__ bsum, int N) {
  __shared__ int ss[256];
  int t = threadIdx.x;
  int i = blockIdx.x * 256 + t;
  int tot = 0;
  if (i < N) {
    int run = 0;
#pragma unroll
    for (int k = 0; k < 8; ++k) {
      int c = cntP[k * N + i];
      cntP[k * N + i] = run;       // exclusive offset of copy k
      run += c;
    }
    tot = run;
  }
  ss[t] = tot;
  __syncthreads();
#pragma unroll
  for (int off = 1; off < 256; off <<= 1) {
    int u = (t >= off) ? ss[t - off] : 0;
    __syncthreads();
    ss[t] += u;
    __syncthreads();
  }
  if (i < N) {
    base[i] = ss[t] - tot;         // exclusive within block
    deg[i] = tot;
  }
  if (t == 255) bsum[blockIdx.x] = ss[255];
}

__global__ __launch_bounds__(512) void scan2(int* __restrict__ bsum, int NB) {
  __shared__ int s[512];
  int v = (threadIdx.x < NB) ? bsum[threadIdx.x] : 0;
  s[threadIdx.x] = v;
  __syncthreads();
#pragma unroll
  for (int off = 1; off < 512; off <<= 1) {
    int t = (threadIdx.x >= off) ? s[threadIdx.x - off] : 0;
    __syncthreads();
    s[threadIdx.x] += t;
    __syncthreads();
  }
  if (threadIdx.x < NB) bsum[threadIdx.x] = s[threadIdx.x] - v;
}

__global__ __launch_bounds__(256) void fill(
    const int* __restrict__ row, const int* __restrict__ col,
    const int* __restrict__ rank, const int* __restrict__ base,
    const int* __restrict__ bsum, const int* __restrict__ cntP,
    int* __restrict__ sorted_col, int E, int N, int G1, int ilv) {
  int e = blockIdx.x * 256 + threadIdx.x;
  if (e >= E) return;
  int r = row[e];
  int t9 = e >> 9;                   // 512-edge tail chunk index
  int b = ilv ? ((t9 >> 2) * 5 + (t9 & 3) + 1)   // inverse of interleave map
              : (G1 + t9);
  int copy = b & 7;
  int pos = base[r] + bsum[r >> 8] + cntP[copy * N + r] + rank[e];
  sorted_col[pos] = col[e];
}

__global__ __launch_bounds__(256) void gather(
    const int* __restrict__ base, const int* __restrict__ bsum,
    const int* __restrict__ deg, const int* __restrict__ sorted_col,
    const float* __restrict__ el, const float* __restrict__ er,
    const ushort* __restrict__ Zh, float* __restrict__ out, int N) {
  int t = threadIdx.x;
  int lane = t & 63;
  int n = blockIdx.x * 4 + (t >> 6);
  if (n >= N) return;
  int h = lane & 3;                   // head
  int jj = lane >> 2;                 // edge sub-index within 16-chunk
  int s = base[n] + bsum[n >> 8];
  int d = deg[n];
  int end = s + d;
  float elv = el[((unsigned)n << 2) + h];
  float acc0 = 0.f, acc1 = 0.f, sumA = 0.f;
  const unsigned* Zh32 = (const unsigned*)Zh;
  const unsigned zlane = (unsigned)lane;
  const int bpb = (lane & 3) << 2;    // bpermute byte base: source = jj*4+h

  // phase A for chunk at pp: one exp per (edge,head) -> packed (cl, bf16(xv))
  auto phaseA = [&](int pp) -> unsigned {
    unsigned pkv = 0;
    if (pp + jj < end) {
      int cl = sorted_col[pp + jj];
      float e = elv + er[((unsigned)cl << 2) + h];
      e = fmaxf(e, 0.2f * e);          // LeakyReLU(0.2)
      float x = __expf(e);
      sumA += x;
      pkv = ((unsigned)cl << 15) | (f2bf(x) & 0x7fffu);  // xv>0 -> sign bit 0
    }
    return pkv;
  };

  unsigned pk = (s < end) ? phaseA(s) : 0;
  for (int p = s; p < end; p += 16) {
    // phase B issue: bpermute broadcast + address calc + Zh loads
    float xvb[16];
    unsigned addrv[16];
#pragma unroll
    for (int q = 0; q < 16; ++q) {
      int a = bpb + (q << 4);          // source lane q*4+h
      unsigned bb = (unsigned)__builtin_amdgcn_ds_bpermute(a, (int)pk);
      addrv[q] = ((bb >> 15) << 6) + zlane;
      xvb[q] = bf2f((ushort)(bb & 0x7fffu));
    }
    unsigned zz[16];
#pragma unroll
    for (int q = 0; q < 16; ++q) zz[q] = Zh32[addrv[q]];
    // phase A of NEXT chunk runs here -- hides the 16 outstanding loads.
    int np = p + 16;
    unsigned pk2 = (np < end) ? phaseA(np) : 0;
#pragma unroll
    for (int q = 0; q < 16; ++q) {
      acc0 = fmaf(xvb[q], __builtin_bit_cast(float, zz[q] << 16), acc0);
      acc1 = fmaf(xvb[q], __builtin_bit_cast(float, zz[q] & 0xffff0000u), acc1);
    }
    pk = pk2;
  }
  // reduce denom over the 16 lanes of this head (bits 2..5)
  float sum = sumA;
  sum += __shfl_xor(sum, 4, 64);
  sum += __shfl_xor(sum, 8, 64);
  sum += __shfl_xor(sum, 16, 64);
  sum += __shfl_xor(sum, 32, 64);
  float inv = (d > 0) ? 1.0f / sum : 0.f;
  // lane = o'*4+h exactly -> coalesced stores
  unsigned ob = ((unsigned)n << 7) + zlane;
  __builtin_nontemporal_store(acc0 * inv, &out[ob]);
  __builtin_nontemporal_store(acc1 * inv, &out[ob + 64]);
}

extern "C" void kernel_launch(void* const* d_in, const int* in_sizes, int n_in,
                              void* d_out, int out_size, void* d_ws, size_t ws_size,
                              hipStream_t stream) {
  const float* x   = (const float*)d_in[0];
  const int*   row = (const int*)d_in[1];
  const int*   col = (const int*)d_in[2];
  const float* W   = (const float*)d_in[3];
  const float* b   = (const float*)d_in[4];
  const float* a_l = (const float*)d_in[5];
  const float* a_r = (const float*)d_in[6];
  float* out = (float*)d_out;

  const int N = in_sizes[0] / 128;
  const int E = in_sizes[1];
  const int NB = (N + 255) / 256;

  char* w = (char*)d_ws;
  ushort* Zh       = (ushort*)w;             w += (size_t)N * 128 * 2;
  int*   sorted_col= (int*)w;                w += (size_t)E * 4;
  int*   rank      = (int*)w;                w += (size_t)E * 4;
  float* el        = (float*)w;              w += (size_t)N * 4 * 4;
  float* er        = (float*)w;              w += (size_t)N * 4 * 4;
  int*   cntP      = (int*)w;                w += (size_t)N * 8 * 4;
  int*   deg       = (int*)w;                w += (size_t)N * 4;
  int*   base      = (int*)w;                w += (size_t)N * 4;
  int*   bsum      = (int*)w;                w += 512 * 4;

  hipMemsetAsync(cntP, 0, (size_t)N * 8 * sizeof(int), stream);

  const int G1 = (N + 127) / 128;            // gemm tiles
  const int G2 = (E + 511) / 512;            // 512-edge tail chunks
  const int ilv = ((G1 - 1) * 5 < G1 + G2) ? 1 : 0;
  gemm_deg<<<G1 + G2, 512, 0, stream>>>(x, W, b, a_l, a_r, Zh, el, er,
                                        N, row, cntP, rank, E, G1, ilv);

  nscan<<<NB, 256, 0, stream>>>(cntP, deg, base, bsum, N);
  scan2<<<1, 512, 0, stream>>>(bsum, NB);
  fill<<<(E + 255) / 256, 256, 0, stream>>>(row, col, rank, base, bsum, cntP,
                                            sorted_col, E, N, G1, ilv);
  gather<<<(N + 3) / 4, 256, 0, stream>>>(base, bsum, deg, sorted_col, el, er,
                                          Zh, out, N);
}